// Round 9
// baseline (160.015 us; speedup 1.0000x reference)
//
#include <hip/hip_runtime.h>

#define B_ 8
#define T_ 2048
#define C_ 1024
#define H_ 128
#define BT_ (B_*T_)

typedef unsigned short u16;
typedef unsigned int u32;
typedef __attribute__((ext_vector_type(4))) float f32x4;
typedef __attribute__((ext_vector_type(8))) __bf16 bf16x8;

__device__ __forceinline__ u16 f2bf(float f) {
  u32 u = __float_as_uint(f);
  u += 0x7fffu + ((u >> 16) & 1u);   // round-to-nearest-even
  return (u16)(u >> 16);
}

// async global -> LDS, 16B per lane (dest = wave-uniform base + lane*16)
#define GLL16(g, l) __builtin_amdgcn_global_load_lds( \
    (const __attribute__((address_space(1))) void*)(g), \
    (__attribute__((address_space(3))) void*)(l), 16, 0, 0)

// MFMA 16x16x32 bf16 A/B fragment from row-major bf16 [rows][stride] in GLOBAL:
// lane l -> row (row0 + (l&15)), 8 contiguous k at k0 + (l>>4)*8.
__device__ __forceinline__ bf16x8 load_frag(const u16* base, int stride, int row0, int k0, int lane) {
  const u16* p = base + (size_t)(row0 + (lane & 15)) * stride + k0 + ((lane >> 4) << 3);
  return *reinterpret_cast<const bf16x8*>(p);
}

// native RNE f32->bf16 (compiler emits v_cvt_pk_bf16_f32 pairs)
__device__ __forceinline__ bf16x8 cvt8n(f32x4 lo, f32x4 hi) {
  bf16x8 r;
#pragma unroll
  for (int i = 0; i < 4; i++) { r[i] = (__bf16)lo[i]; r[4 + i] = (__bf16)hi[i]; }
  return r;
}

// ---------------- Kernel 0: W (f32) -> W^T (bf16) ----------------
__global__ void wt_kernel(const float* __restrict__ Wq, const float* __restrict__ Wk,
                          const float* __restrict__ Wv, u16* __restrict__ wt) {
  int mat = blockIdx.y;
  const float* W = (mat == 0) ? Wq : (mat == 1) ? Wk : Wv;
  int i = blockIdx.x * 256 + threadIdx.x;
  int h = i >> 10;
  int c = i & 1023;
  wt[mat * (C_ * H_) + i] = f2bf(W[c * H_ + h]);
}

// ---------------- Kernel 1: QKV projection, single-round fat blocks ----------
// (unchanged — proven in rounds 5-8)
__global__ __launch_bounds__(512, 4) void qkv_gemm(const float* __restrict__ x, const u16* __restrict__ wt,
                                                   u16* __restrict__ q, u16* __restrict__ k2,
                                                   u16* __restrict__ vt) {
  __shared__ __align__(16) float As[2][64 * 64];   // 2 x 16 KiB (f32)
  __shared__ __align__(16) u16 Bs[2][192 * 64];    // 2 x 24 KiB (bf16)
  int t = threadIdx.x;
  int lane = t & 63, w = t >> 6;
  int wm = w >> 2, wn = w & 3;           // 2M x 4N wave grid
  int quad = lane >> 4, col = lane & 15;
  int m0 = blockIdx.x * 64;
  int nb = blockIdx.y * 192;             // column base into fused [q|k|v] (384)

  int arow = t >> 4;
  int acg = (t & 15) ^ (arow & 15);
  const float* ax0 = x + (size_t)(m0 + arow) * C_ + acg * 4;
  const float* ax1 = ax0 + (size_t)32 * C_;
  int brow = t >> 3;
  int bcg = (t & 7) ^ (brow & 7);
  const u16* bw0 = wt + (size_t)(nb + brow) * C_ + bcg * 8;
  const u16* bw1 = bw0 + (size_t)64 * C_;
  const u16* bw2 = bw0 + (size_t)128 * C_;

#define STAGE(st, buf) do { \
    int ko_ = (st) * 64; \
    GLL16(ax0 + ko_, &As[buf][t * 4]); \
    GLL16(ax1 + ko_, &As[buf][2048 + t * 4]); \
    GLL16(bw0 + ko_, &Bs[buf][t * 8]); \
    GLL16(bw1 + ko_, &Bs[buf][4096 + t * 8]); \
    GLL16(bw2 + ko_, &Bs[buf][8192 + t * 8]); \
  } while (0)

  STAGE(0, 0);

  f32x4 acc[2][3] = {};
#pragma unroll 2
  for (int kk = 0; kk < 16; kk++) {
    int cur = kk & 1;
    __syncthreads();
    if (kk + 1 < 16) STAGE(kk + 1, cur ^ 1);
    const float* Ab = &As[cur][0];
    const u16* Bb = &Bs[cur][0];
#pragma unroll
    for (int ks = 0; ks < 2; ks++) {
      bf16x8 af[2], bfr[3];
#pragma unroll
      for (int mt = 0; mt < 2; mt++) {
        int rr = wm * 32 + mt * 16 + col;
        int s0 = (ks * 8 + quad * 2) ^ (rr & 15);
        int s1 = s0 ^ 1;
        f32x4 lo = *reinterpret_cast<const f32x4*>(Ab + rr * 64 + s0 * 4);
        f32x4 hi = *reinterpret_cast<const f32x4*>(Ab + rr * 64 + s1 * 4);
        af[mt] = cvt8n(lo, hi);
      }
#pragma unroll
      for (int nt = 0; nt < 3; nt++) {
        int rr = wn * 48 + nt * 16 + col;
        int sl = (ks * 4 + quad) ^ (rr & 7);
        bfr[nt] = *reinterpret_cast<const bf16x8*>(Bb + rr * 64 + sl * 8);
      }
#pragma unroll
      for (int mt = 0; mt < 2; mt++)
#pragma unroll
        for (int nt = 0; nt < 3; nt++)
          acc[mt][nt] = __builtin_amdgcn_mfma_f32_16x16x32_bf16(af[mt], bfr[nt], acc[mt][nt], 0, 0, 0);
    }
  }
#undef STAGE

#pragma unroll
  for (int mt = 0; mt < 2; mt++) {
    int row0 = m0 + wm * 32 + mt * 16 + quad * 4;
#pragma unroll
    for (int nt = 0; nt < 3; nt++) {
      int n = nb + wn * 48 + nt * 16 + col;
      int mat = n >> 7, h = n & 127;
      if (mat == 0) {
#pragma unroll
        for (int r = 0; r < 4; r++) q[(size_t)(row0 + r) * H_ + h] = f2bf(acc[mt][nt][r]);
      } else if (mat == 1) {
#pragma unroll
        for (int r = 0; r < 4; r++) k2[(size_t)(row0 + r) * H_ + h] = f2bf(acc[mt][nt][r]);
      } else {
        int bb = row0 >> 11, tt = row0 & 2047;
        ushort4 pk;
        pk.x = f2bf(acc[mt][nt][0]); pk.y = f2bf(acc[mt][nt][1]);
        pk.z = f2bf(acc[mt][nt][2]); pk.w = f2bf(acc[mt][nt][3]);
        *reinterpret_cast<ushort4*>(&vt[((size_t)bb * H_ + h) * T_ + tt]) = pk;
      }
    }
  }
}

// ---------------- Kernel 2: causal flash attention, fat waves ----------------
// Round-8 lesson: attn is LDS-issue-bound and K/V fragment reads are repeated
// identically by every wave. Fix: 4 waves x 32 q-rows each (QBLK=128, 256 thr).
// K/V frags are read ONCE per wave and reused across the wave's two 16-row
// halves (K 8 + V 8 reads/iter for 32 MFMA vs r7's for 16). P roundtrip packed:
// cols {c, c+16} as one u32 -> [16][20] u32 buffer (8 writes + 4 b128 reads +
// VALU unpack vs 16 scalar writes + 2 reads). ~1.0 LDS instr per q-row per
// iter vs r7's 1.81. Grid 16qt x 4s x 8b = 512 blocks, LDS 48.1KB ->
// 2 blocks/CU single-round residency; launch_bounds(256,2) -> 256 VGPR.
// NO-MAX softmax as before. Partials: unnormalized O + l; combine sums 4.
__global__ __launch_bounds__(256, 2) void attn_part(const u16* __restrict__ q, const u16* __restrict__ k,
                                                    const u16* __restrict__ vt,
                                                    float* __restrict__ Op, float* __restrict__ lsum) {
  __shared__ __align__(16) u16 Ks[2][32 * 136];    // 17,408 B
  __shared__ __align__(16) u16 Vs[2][128 * 40];    // 20,480 B
  __shared__ __align__(16) u32 P32[4][2][16 * 20]; // 10,240 B (u32: cols {c, c+16})
  int t = threadIdx.x;
  int lane = t & 63, w = t >> 6;                   // 4 waves x 32 q-rows
  int quad = lane >> 4, col = lane & 15;
  int bx = blockIdx.x;
  int qt = 15 - (bx >> 5);                 // LPT: big tiles first
  int s = (bx >> 3) & 3;
  int b = bx & 7;
  const float scale = 0.08838834764831845f; // 1/sqrt(128)

  // k-range: 4*(qt+1) tiles of 32 keys, split evenly 4 ways
  int it0 = s * (qt + 1);
  int it1 = it0 + (qt + 1);

  int krow0 = t >> 4, ke = (t & 15) * 8;   // 32 rows x 128 cols, 2 uint4/thr
  int krow1 = krow0 + 16;
  int vrow0 = t >> 2, ve = (t & 3) * 8;    // 128 rows x 32 cols, 2 uint4/thr
  int vrow1 = vrow0 + 64;

  int qrow0 = b * T_ + qt * 128 + w * 32;
  bf16x8 qf[2][4];
#pragma unroll
  for (int hf = 0; hf < 2; hf++)
#pragma unroll
    for (int ks = 0; ks < 4; ks++)
      qf[hf][ks] = load_frag(q, H_, qrow0 + hf * 16, ks * 32, lane);

  f32x4 o[2][8] = {};
  float l[8] = {};                         // per-lane partial sums [hf*4+r]
  int myqrow = qt * 128 + w * 32 + quad * 4;

  // prologue: stage iter it0 into buffer 0
  {
    const u16* kb = k + (size_t)(b * T_ + it0 * 32) * H_;
    *reinterpret_cast<uint4*>(&Ks[0][krow0 * 136 + ke]) = *reinterpret_cast<const uint4*>(kb + (size_t)krow0 * 128 + ke);
    *reinterpret_cast<uint4*>(&Ks[0][krow1 * 136 + ke]) = *reinterpret_cast<const uint4*>(kb + (size_t)krow1 * 128 + ke);
    const u16* vb = vt + (size_t)b * H_ * T_ + it0 * 32;
    *reinterpret_cast<uint4*>(&Vs[0][vrow0 * 40 + ve]) = *reinterpret_cast<const uint4*>(vb + (size_t)vrow0 * T_ + ve);
    *reinterpret_cast<uint4*>(&Vs[0][vrow1 * 40 + ve]) = *reinterpret_cast<const uint4*>(vb + (size_t)vrow1 * T_ + ve);
  }

  for (int kt = it0; kt < it1; kt++) {
    int cur = (kt - it0) & 1;
    __syncthreads();
    bool more = (kt + 1 < it1);
    uint4 kc0, kc1, vc0, vc1;
    if (more) {
      const u16* kb = k + (size_t)(b * T_ + (kt + 1) * 32) * H_;
      kc0 = *reinterpret_cast<const uint4*>(kb + (size_t)krow0 * 128 + ke);
      kc1 = *reinterpret_cast<const uint4*>(kb + (size_t)krow1 * 128 + ke);
      const u16* vb = vt + (size_t)b * H_ * T_ + (kt + 1) * 32;
      vc0 = *reinterpret_cast<const uint4*>(vb + (size_t)vrow0 * T_ + ve);
      vc1 = *reinterpret_cast<const uint4*>(vb + (size_t)vrow1 * T_ + ve);
    }

    // ---- S = Q K^T from LDS; K frags read once, used by both halves ----
    f32x4 s0[2] = {}, s1[2] = {};
#pragma unroll
    for (int ks = 0; ks < 4; ks++) {
      bf16x8 kb0 = *reinterpret_cast<const bf16x8*>(&Ks[cur][col * 136 + ks * 32 + quad * 8]);
      bf16x8 kb1 = *reinterpret_cast<const bf16x8*>(&Ks[cur][(col + 16) * 136 + ks * 32 + quad * 8]);
#pragma unroll
      for (int hf = 0; hf < 2; hf++) {
        s0[hf] = __builtin_amdgcn_mfma_f32_16x16x32_bf16(qf[hf][ks], kb0, s0[hf], 0, 0, 0);
        s1[hf] = __builtin_amdgcn_mfma_f32_16x16x32_bf16(qf[hf][ks], kb1, s1[hf], 0, 0, 0);
      }
    }

    // ---- scale + causal mask + exp; packed P write (u32 = cols {c, c+16}) ----
    int kcol0 = kt * 32 + col;
#pragma unroll
    for (int hf = 0; hf < 2; hf++) {
      u32* Pb = &P32[w][hf][0];
#pragma unroll
      for (int r = 0; r < 4; r++) {
        int qr = myqrow + hf * 16 + r;
        float a0 = fminf(s0[hf][r] * scale, 30.f);
        float a1 = fminf(s1[hf][r] * scale, 30.f);
        a0 = (kcol0      > qr) ? -1e30f : a0;
        a1 = (kcol0 + 16 > qr) ? -1e30f : a1;
        float p0 = __expf(a0);
        float p1 = __expf(a1);
        l[hf * 4 + r] += p0 + p1;
        Pb[(quad * 4 + r) * 20 + col] = (u32)f2bf(p0) | ((u32)f2bf(p1) << 16);
      }
    }
    asm volatile("" ::: "memory");
    __builtin_amdgcn_s_waitcnt(0xc07f);   // lgkmcnt(0); vmcnt untouched
    asm volatile("" ::: "memory");

    // ---- P read: 2x b128 per half + lo/hi unpack ----
    bf16x8 pf[2];
    int j0 = (quad & 1) * 8;
#pragma unroll
    for (int hf = 0; hf < 2; hf++) {
      const u32* Pb = &P32[w][hf][0];
      uint4 wa = *reinterpret_cast<const uint4*>(&Pb[col * 20 + j0]);
      uint4 wb = *reinterpret_cast<const uint4*>(&Pb[col * 20 + j0 + 4]);
      u32 sarr[8] = {wa.x, wa.y, wa.z, wa.w, wb.x, wb.y, wb.z, wb.w};
      union { u32 u[4]; bf16x8 v; } pu;
#pragma unroll
      for (int i = 0; i < 4; i++) {
        u32 a = sarr[2 * i], c = sarr[2 * i + 1];
        pu.u[i] = (quad < 2) ? ((a & 0xffffu) | (c << 16))
                             : ((a >> 16) | (c & 0xffff0000u));
      }
      pf[hf] = pu.v;
    }

    // ---- O += P V; V frags read once, used by both halves ----
#pragma unroll
    for (int ht = 0; ht < 8; ht++) {
      bf16x8 vf = *reinterpret_cast<const bf16x8*>(&Vs[cur][(ht * 16 + col) * 40 + quad * 8]);
      o[0][ht] = __builtin_amdgcn_mfma_f32_16x16x32_bf16(pf[0], vf, o[0][ht], 0, 0, 0);
      o[1][ht] = __builtin_amdgcn_mfma_f32_16x16x32_bf16(pf[1], vf, o[1][ht], 0, 0, 0);
    }

    if (more) {
      int nxt = cur ^ 1;
      *reinterpret_cast<uint4*>(&Ks[nxt][krow0 * 136 + ke]) = kc0;
      *reinterpret_cast<uint4*>(&Ks[nxt][krow1 * 136 + ke]) = kc1;
      *reinterpret_cast<uint4*>(&Vs[nxt][vrow0 * 40 + ve]) = vc0;
      *reinterpret_cast<uint4*>(&Vs[nxt][vrow1 * 40 + ve]) = vc1;
    }
  }

  // ---- one deferred row-sum reduction for l ----
#pragma unroll
  for (int i = 0; i < 8; i++) {
    float v = l[i];
    v += __shfl_xor(v, 1);
    v += __shfl_xor(v, 2);
    v += __shfl_xor(v, 4);
    v += __shfl_xor(v, 8);
    l[i] = v;
  }

  // ---- write partials (unnormalized O, l) ----
  int tile = (s * 8 + b) * 16 + qt;        // 0..511
  float* Orow = Op + (size_t)tile * (128 * 128);
  float* lrow = lsum + (size_t)tile * 128;
#pragma unroll
  for (int hf = 0; hf < 2; hf++) {
    int rowin0 = w * 32 + hf * 16 + quad * 4;
    if (col == 0) {
#pragma unroll
      for (int r = 0; r < 4; r++) lrow[rowin0 + r] = l[hf * 4 + r];
    }
#pragma unroll
    for (int ht = 0; ht < 8; ht++) {
#pragma unroll
      for (int r = 0; r < 4; r++)
        Orow[(size_t)(rowin0 + r) * 128 + ht * 16 + col] = o[hf][ht][r];
    }
  }
}

// ---------------- Kernel 3: combine (sum of 4 partials, 128-row tiles) -------
__global__ __launch_bounds__(256) void attn_comb(const float* __restrict__ Op, const float* __restrict__ lsum,
                                                 float* __restrict__ out) {
  int bx = blockIdx.x;                     // 0..127: b*16 + qt
  int b = bx >> 4, qt = bx & 15;
  int t = threadIdx.x;
  int h = t & 127, half = t >> 7;
  int tile0 = b * 16 + qt;
#pragma unroll 4
  for (int rr = 0; rr < 64; rr++) {
    int row = half * 64 + rr;
    float ls = 0.f, v = 0.f;
#pragma unroll
    for (int p = 0; p < 4; p++) {
      int tp = tile0 + p * 128;
      ls += lsum[tp * 128 + row];
      v  += Op[(size_t)tp * 16384 + row * 128 + h];
    }
    out[((size_t)(b * T_ + qt * 128 + row)) * H_ + h] = v / ls;
  }
}

extern "C" void kernel_launch(void* const* d_in, const int* in_sizes, int n_in,
                              void* d_out, int out_size, void* d_ws, size_t ws_size,
                              hipStream_t stream) {
  (void)in_sizes; (void)n_in; (void)out_size; (void)ws_size;
  const float* x  = (const float*)d_in[0];
  const float* Wq = (const float*)d_in[1];
  const float* Wk = (const float*)d_in[2];
  const float* Wv = (const float*)d_in[3];
  u16* ws = (u16*)d_ws;
  u16* q  = ws;                               // [BT][H]      4 MiB (bf16)
  u16* k  = ws + (size_t)BT_ * H_;            // [BT][H]      4 MiB (bf16)
  u16* vt = ws + 2 * (size_t)BT_ * H_;        // [B][H][T]    4 MiB (bf16)
  u16* wt = ws + 3 * (size_t)BT_ * H_;        // [3][H][C]  768 KiB (bf16)
  float* Op = (float*)(ws + 3 * (size_t)BT_ * H_ + 3 * C_ * H_); // [512][128][128] f32, 32 MiB
  float* lsum = Op + (size_t)512 * 128 * 128; // [512][128] f32, 256 KiB
  float* out = (float*)d_out;

  wt_kernel<<<dim3(512, 3), 256, 0, stream>>>(Wq, Wk, Wv, wt);
  qkv_gemm<<<dim3(BT_ / 64, 2), 512, 0, stream>>>(x, wt, q, k, vt);
  attn_part<<<dim3(512), 256, 0, stream>>>(q, k, vt, Op, lsum);
  attn_comb<<<dim3(128), 256, 0, stream>>>(Op, lsum, out);
}

// Round 10
// 151.734 us; speedup vs baseline: 1.0546x; 1.0546x over previous
//
#include <hip/hip_runtime.h>

#define B_ 8
#define T_ 2048
#define C_ 1024
#define H_ 128
#define BT_ (B_*T_)

typedef unsigned short u16;
typedef unsigned int u32;
typedef __attribute__((ext_vector_type(4))) float f32x4;
typedef __attribute__((ext_vector_type(8))) __bf16 bf16x8;

__device__ __forceinline__ u16 f2bf(float f) {
  u32 u = __float_as_uint(f);
  u += 0x7fffu + ((u >> 16) & 1u);   // round-to-nearest-even
  return (u16)(u >> 16);
}

// async global -> LDS, 16B per lane (dest = wave-uniform base + lane*16)
#define GLL16(g, l) __builtin_amdgcn_global_load_lds( \
    (const __attribute__((address_space(1))) void*)(g), \
    (__attribute__((address_space(3))) void*)(l), 16, 0, 0)

// MFMA 16x16x32 bf16 A/B fragment from row-major bf16 [rows][stride] in GLOBAL:
// lane l -> row (row0 + (l&15)), 8 contiguous k at k0 + (l>>4)*8.
__device__ __forceinline__ bf16x8 load_frag(const u16* base, int stride, int row0, int k0, int lane) {
  const u16* p = base + (size_t)(row0 + (lane & 15)) * stride + k0 + ((lane >> 4) << 3);
  return *reinterpret_cast<const bf16x8*>(p);
}

// native RNE f32->bf16 (compiler emits v_cvt_pk_bf16_f32 pairs)
__device__ __forceinline__ bf16x8 cvt8n(f32x4 lo, f32x4 hi) {
  bf16x8 r;
#pragma unroll
  for (int i = 0; i < 4; i++) { r[i] = (__bf16)lo[i]; r[4 + i] = (__bf16)hi[i]; }
  return r;
}

// ---------------- Kernel 0: W (f32) -> W^T (bf16) ----------------
__global__ void wt_kernel(const float* __restrict__ Wq, const float* __restrict__ Wk,
                          const float* __restrict__ Wv, u16* __restrict__ wt) {
  int mat = blockIdx.y;
  const float* W = (mat == 0) ? Wq : (mat == 1) ? Wk : Wv;
  int i = blockIdx.x * 256 + threadIdx.x;
  int h = i >> 10;
  int c = i & 1023;
  wt[mat * (C_ * H_) + i] = f2bf(W[c * H_ + h]);
}

// ---------------- Kernel 1: QKV projection, single-round fat blocks ----------
// (unchanged — proven in rounds 5-9)
__global__ __launch_bounds__(512, 4) void qkv_gemm(const float* __restrict__ x, const u16* __restrict__ wt,
                                                   u16* __restrict__ q, u16* __restrict__ k2,
                                                   u16* __restrict__ vt) {
  __shared__ __align__(16) float As[2][64 * 64];   // 2 x 16 KiB (f32)
  __shared__ __align__(16) u16 Bs[2][192 * 64];    // 2 x 24 KiB (bf16)
  int t = threadIdx.x;
  int lane = t & 63, w = t >> 6;
  int wm = w >> 2, wn = w & 3;           // 2M x 4N wave grid
  int quad = lane >> 4, col = lane & 15;
  int m0 = blockIdx.x * 64;
  int nb = blockIdx.y * 192;             // column base into fused [q|k|v] (384)

  int arow = t >> 4;
  int acg = (t & 15) ^ (arow & 15);
  const float* ax0 = x + (size_t)(m0 + arow) * C_ + acg * 4;
  const float* ax1 = ax0 + (size_t)32 * C_;
  int brow = t >> 3;
  int bcg = (t & 7) ^ (brow & 7);
  const u16* bw0 = wt + (size_t)(nb + brow) * C_ + bcg * 8;
  const u16* bw1 = bw0 + (size_t)64 * C_;
  const u16* bw2 = bw0 + (size_t)128 * C_;

#define STAGE(st, buf) do { \
    int ko_ = (st) * 64; \
    GLL16(ax0 + ko_, &As[buf][t * 4]); \
    GLL16(ax1 + ko_, &As[buf][2048 + t * 4]); \
    GLL16(bw0 + ko_, &Bs[buf][t * 8]); \
    GLL16(bw1 + ko_, &Bs[buf][4096 + t * 8]); \
    GLL16(bw2 + ko_, &Bs[buf][8192 + t * 8]); \
  } while (0)

  STAGE(0, 0);

  f32x4 acc[2][3] = {};
#pragma unroll 2
  for (int kk = 0; kk < 16; kk++) {
    int cur = kk & 1;
    __syncthreads();
    if (kk + 1 < 16) STAGE(kk + 1, cur ^ 1);
    const float* Ab = &As[cur][0];
    const u16* Bb = &Bs[cur][0];
#pragma unroll
    for (int ks = 0; ks < 2; ks++) {
      bf16x8 af[2], bfr[3];
#pragma unroll
      for (int mt = 0; mt < 2; mt++) {
        int rr = wm * 32 + mt * 16 + col;
        int s0 = (ks * 8 + quad * 2) ^ (rr & 15);
        int s1 = s0 ^ 1;
        f32x4 lo = *reinterpret_cast<const f32x4*>(Ab + rr * 64 + s0 * 4);
        f32x4 hi = *reinterpret_cast<const f32x4*>(Ab + rr * 64 + s1 * 4);
        af[mt] = cvt8n(lo, hi);
      }
#pragma unroll
      for (int nt = 0; nt < 3; nt++) {
        int rr = wn * 48 + nt * 16 + col;
        int sl = (ks * 4 + quad) ^ (rr & 7);
        bfr[nt] = *reinterpret_cast<const bf16x8*>(Bb + rr * 64 + sl * 8);
      }
#pragma unroll
      for (int mt = 0; mt < 2; mt++)
#pragma unroll
        for (int nt = 0; nt < 3; nt++)
          acc[mt][nt] = __builtin_amdgcn_mfma_f32_16x16x32_bf16(af[mt], bfr[nt], acc[mt][nt], 0, 0, 0);
    }
  }
#undef STAGE

#pragma unroll
  for (int mt = 0; mt < 2; mt++) {
    int row0 = m0 + wm * 32 + mt * 16 + quad * 4;
#pragma unroll
    for (int nt = 0; nt < 3; nt++) {
      int n = nb + wn * 48 + nt * 16 + col;
      int mat = n >> 7, h = n & 127;
      if (mat == 0) {
#pragma unroll
        for (int r = 0; r < 4; r++) q[(size_t)(row0 + r) * H_ + h] = f2bf(acc[mt][nt][r]);
      } else if (mat == 1) {
#pragma unroll
        for (int r = 0; r < 4; r++) k2[(size_t)(row0 + r) * H_ + h] = f2bf(acc[mt][nt][r]);
      } else {
        int bb = row0 >> 11, tt = row0 & 2047;
        ushort4 pk;
        pk.x = f2bf(acc[mt][nt][0]); pk.y = f2bf(acc[mt][nt][1]);
        pk.z = f2bf(acc[mt][nt][2]); pk.w = f2bf(acc[mt][nt][3]);
        *reinterpret_cast<ushort4*>(&vt[((size_t)bb * H_ + h) * T_ + tt]) = pk;
      }
    }
  }
}

// ---------------- Kernel 2: causal flash attention, 4-way K-split ------------
// Round-9 lesson: r7's geometry (QBLK=64, 4 waves, 4-way split, 4 blocks/CU)
// is a local optimum — r8/r9 reshapes both regressed. This is r7 EXACTLY
// except the K staging path: reg-staged (2 loads + 2 ds_writes + vmcnt dep)
// -> 2x global_load_lds into LINEAR Ks[2][32][128] with both-sides XOR
// (source granule (t&15)^(row&15), read slot (ks*4+quad)^col => exact 2-way
// aliasing = free). Issue order per iter: V reg-loads first, then K GLL16s,
// so V's ds_write waits vmcnt(2) and K loads stay in flight until the next
// barrier. LDS 39,936 B -> 4 blocks/CU kept.
// NO-MAX softmax as before. Partials: unnormalized O + l; combine sums 4.
__global__ __launch_bounds__(256, 4) void attn_part(const u16* __restrict__ q, const u16* __restrict__ k,
                                                    const u16* __restrict__ vt,
                                                    float* __restrict__ Op, float* __restrict__ lsum) {
  __shared__ __align__(16) u16 Ks[2][32 * 128];   // 16,384 B linear (GLL16)
  __shared__ __align__(16) u16 Vs[2][128 * 36];   // 18,432 B
  __shared__ __align__(16) u16 P[4][16 * 40];     //  5,120 B
  int t = threadIdx.x;
  int lane = t & 63, w = t >> 6;
  int quad = lane >> 4, col = lane & 15;
  int bx = blockIdx.x;
  int qt = 31 - (bx >> 5);                 // LPT: big tiles first
  int s = (bx >> 3) & 3;
  int b = bx & 7;
  const float scale = 0.08838834764831845f; // 1/sqrt(128)

  int nk = 2 * (qt + 1);
  int it0 = (s * nk) >> 2;
  int it1 = ((s + 1) * nk) >> 2;

  // K staging: thread t covers row (t>>4) (+16 on issue 1), 16B granule t&15;
  // source pre-swizzled so LDS slot g of row r holds global granule g^(r&15).
  size_t koff = (size_t)(t >> 4) * 128 + (size_t)((((t & 15) ^ ((t >> 4) & 15))) << 3);
  const u16* kb_b = k + (size_t)b * T_ * H_;

  int vrow0 = t >> 2, ve = (t & 3) * 8;
  int vrow1 = vrow0 + 64;

  int qrow0 = b * T_ + qt * 64 + w * 16;
  bf16x8 qf[4];
#pragma unroll
  for (int ks = 0; ks < 4; ks++) qf[ks] = load_frag(q, H_, qrow0, ks * 32, lane);

  f32x4 o[8] = {};
  float l[4] = {0.f, 0.f, 0.f, 0.f};       // per-lane partial sums
  int myqrow = qt * 64 + w * 16 + quad * 4;

  // prologue: stage iter it0 into buffer 0 (skip if empty range)
  if (it0 < it1) {
    const u16* vb = vt + (size_t)b * H_ * T_ + it0 * 32;
    *reinterpret_cast<uint4*>(&Vs[0][vrow0 * 36 + ve]) = *reinterpret_cast<const uint4*>(vb + (size_t)vrow0 * T_ + ve);
    *reinterpret_cast<uint4*>(&Vs[0][vrow1 * 36 + ve]) = *reinterpret_cast<const uint4*>(vb + (size_t)vrow1 * T_ + ve);
    const u16* kb = kb_b + (size_t)it0 * 32 * H_;
    GLL16(kb + koff, &Ks[0][t * 8]);
    GLL16(kb + koff + 2048, &Ks[0][2048 + t * 8]);   // rows +16
  }

  for (int kt = it0; kt < it1; kt++) {
    int cur = (kt - it0) & 1;
    __syncthreads();                       // drains K GLL16s (full-iter flight)
    bool more = (kt + 1 < it1);
    uint4 vc0, vc1;
    if (more) {
      int nxt = cur ^ 1;
      const u16* vb = vt + (size_t)b * H_ * T_ + (kt + 1) * 32;
      vc0 = *reinterpret_cast<const uint4*>(vb + (size_t)vrow0 * T_ + ve);
      vc1 = *reinterpret_cast<const uint4*>(vb + (size_t)vrow1 * T_ + ve);
      const u16* kb = kb_b + (size_t)(kt + 1) * 32 * H_;
      GLL16(kb + koff, &Ks[nxt][t * 8]);
      GLL16(kb + koff + 2048, &Ks[nxt][2048 + t * 8]);
    }

    // ---- S = Q K^T from LDS (XOR-slot reads; rows col and col+16 share xor) ----
    f32x4 s0 = {}, s1 = {};
#pragma unroll
    for (int ks = 0; ks < 4; ks++) {
      int sl = ((ks * 4 + quad) ^ col) * 8;
      bf16x8 kb0 = *reinterpret_cast<const bf16x8*>(&Ks[cur][col * 128 + sl]);
      bf16x8 kb1 = *reinterpret_cast<const bf16x8*>(&Ks[cur][(col + 16) * 128 + sl]);
      s0 = __builtin_amdgcn_mfma_f32_16x16x32_bf16(qf[ks], kb0, s0, 0, 0, 0);
      s1 = __builtin_amdgcn_mfma_f32_16x16x32_bf16(qf[ks], kb1, s1, 0, 0, 0);
    }

    // ---- scale + causal mask + exp (no max subtraction) ----
    float pv[8];
    int kcol0 = kt * 32 + col;
#pragma unroll
    for (int r = 0; r < 4; r++) {
      int qr = myqrow + r;
      float a0 = fminf(s0[r] * scale, 30.f);
      float a1 = fminf(s1[r] * scale, 30.f);
      a0 = (kcol0      > qr) ? -1e30f : a0;
      a1 = (kcol0 + 16 > qr) ? -1e30f : a1;
      float p0 = __expf(a0);
      float p1 = __expf(a1);
      pv[r] = p0; pv[4 + r] = p1;
      l[r] += p0 + p1;
    }

    // ---- P (C-layout) -> wave-private LDS -> A-frag; lgkm wait only ----
    u16* Pb = &P[w][0];
#pragma unroll
    for (int r = 0; r < 4; r++) {
      Pb[(quad * 4 + r) * 40 + col] = f2bf(pv[r]);
      Pb[(quad * 4 + r) * 40 + col + 16] = f2bf(pv[4 + r]);
    }
    asm volatile("" ::: "memory");
    __builtin_amdgcn_s_waitcnt(0xc07f);   // lgkmcnt(0); vmcnt untouched
    asm volatile("" ::: "memory");
    bf16x8 pf = *reinterpret_cast<const bf16x8*>(&Pb[col * 40 + (quad << 3)]);

    // ---- O += P V (no rescale needed) ----
#pragma unroll
    for (int ht = 0; ht < 8; ht++) {
      bf16x8 vf = *reinterpret_cast<const bf16x8*>(&Vs[cur][(ht * 16 + col) * 36 + quad * 8]);
      o[ht] = __builtin_amdgcn_mfma_f32_16x16x32_bf16(pf, vf, o[ht], 0, 0, 0);
    }

    if (more) {
      int nxt = cur ^ 1;
      *reinterpret_cast<uint4*>(&Vs[nxt][vrow0 * 36 + ve]) = vc0;
      *reinterpret_cast<uint4*>(&Vs[nxt][vrow1 * 36 + ve]) = vc1;
    }
  }

  // ---- one deferred row-sum reduction for l ----
#pragma unroll
  for (int r = 0; r < 4; r++) {
    float v = l[r];
    v += __shfl_xor(v, 1);
    v += __shfl_xor(v, 2);
    v += __shfl_xor(v, 4);
    v += __shfl_xor(v, 8);
    l[r] = v;
  }

  // ---- write partials (unnormalized O, l) ----
  int tile = (s * 8 + b) * 32 + qt;
  float* Orow = Op + (size_t)tile * (64 * 128);
  float* lrow = lsum + (size_t)tile * 64;
  int rowin0 = w * 16 + quad * 4;
  if (col == 0) {
#pragma unroll
    for (int r = 0; r < 4; r++) lrow[rowin0 + r] = l[r];
  }
#pragma unroll
  for (int ht = 0; ht < 8; ht++) {
#pragma unroll
    for (int r = 0; r < 4; r++)
      Orow[(size_t)(rowin0 + r) * 128 + ht * 16 + col] = o[ht][r];
  }
}

// ---------------- Kernel 3: combine (sum of 4 partials) ----------------
__global__ __launch_bounds__(256) void attn_comb(const float* __restrict__ Op, const float* __restrict__ lsum,
                                                 float* __restrict__ out) {
  int bx = blockIdx.x;
  int b = bx >> 5, qt = bx & 31;
  int t = threadIdx.x;
  int h = t & 127, half = t >> 7;
  int tile0 = b * 32 + qt;
#pragma unroll 4
  for (int rr = 0; rr < 32; rr++) {
    int row = half * 32 + rr;
    float ls = 0.f, v = 0.f;
#pragma unroll
    for (int p = 0; p < 4; p++) {
      int tp = tile0 + p * 256;
      ls += lsum[tp * 64 + row];
      v  += Op[(size_t)tp * 8192 + row * 128 + h];
    }
    out[((size_t)(b * T_ + qt * 64 + row)) * H_ + h] = v / ls;
  }
}

extern "C" void kernel_launch(void* const* d_in, const int* in_sizes, int n_in,
                              void* d_out, int out_size, void* d_ws, size_t ws_size,
                              hipStream_t stream) {
  (void)in_sizes; (void)n_in; (void)out_size; (void)ws_size;
  const float* x  = (const float*)d_in[0];
  const float* Wq = (const float*)d_in[1];
  const float* Wk = (const float*)d_in[2];
  const float* Wv = (const float*)d_in[3];
  u16* ws = (u16*)d_ws;
  u16* q  = ws;                               // [BT][H]      4 MiB (bf16)
  u16* k  = ws + (size_t)BT_ * H_;            // [BT][H]      4 MiB (bf16)
  u16* vt = ws + 2 * (size_t)BT_ * H_;        // [B][H][T]    4 MiB (bf16)
  u16* wt = ws + 3 * (size_t)BT_ * H_;        // [3][H][C]  768 KiB (bf16)
  float* Op = (float*)(ws + 3 * (size_t)BT_ * H_ + 3 * C_ * H_); // [1024][64][128] f32, 32 MiB
  float* lsum = Op + (size_t)1024 * 64 * 128; // [1024][64] f32, 256 KiB
  float* out = (float*)d_out;

  wt_kernel<<<dim3(512, 3), 256, 0, stream>>>(Wq, Wk, Wv, wt);
  qkv_gemm<<<dim3(BT_ / 64, 2), 512, 0, stream>>>(x, wt, q, k, vt);
  attn_part<<<dim3(1024), 256, 0, stream>>>(q, k, vt, Op, lsum);
  attn_comb<<<dim3(256), 256, 0, stream>>>(Op, lsum, out);
}